// Round 16
// baseline (49.734 us; speedup 1.0000x reference)
//
#include <hip/hip_runtime.h>
#include <math.h>

#define NQ 14
#define NSTATE (1 << 14)
#define DEPTH  6
#define NT     1024             // 16 waves/block; ONE block/CU (128 KiB state)

typedef float v2f __attribute__((ext_vector_type(2)));

// dword-index swizzle: XOR bits 6,7,8 into 2,3,4 (GF(2)-linear)
__device__ __forceinline__ int swz(int n) { return n ^ ((n >> 4) & 28); }

// fused CNOT ladders (even after odd): m = sigma_e(sigma_o(n))
__device__ __forceinline__ int sigma(int n) {
    int m = n ^ ((n & 0x1554) >> 1);
    return m ^ ((m & 0x2AAA) >> 1);
}

// ---- VOP3P packed helpers (r11/r15-proven); cs = (c, s) ----
__device__ __forceinline__ v2f pkmul_cc(v2f a, v2f cs) {   // d = a * c
    v2f d;
    asm("v_pk_mul_f32 %0, %1, %2 op_sel:[0,0] op_sel_hi:[1,0]"
        : "=v"(d) : "v"(a), "v"(cs));
    return d;
}
__device__ __forceinline__ v2f pkmul_ss(v2f a, v2f cs) {   // d = a * s
    v2f d;
    asm("v_pk_mul_f32 %0, %1, %2 op_sel:[0,1] op_sel_hi:[1,1]"
        : "=v"(d) : "v"(a), "v"(cs));
    return d;
}
__device__ __forceinline__ v2f pkfma_cc(v2f a, v2f cs, v2f acc) {  // a*c + acc
    v2f d;
    asm("v_pk_fma_f32 %0, %1, %2, %3 op_sel:[0,0,0] op_sel_hi:[1,0,1]"
        : "=v"(d) : "v"(a), "v"(cs), "v"(acc));
    return d;
}
__device__ __forceinline__ v2f pkfma_nss(v2f a, v2f cs, v2f acc) { // -(a*s) + acc
    v2f d;
    asm("v_pk_fma_f32 %0, %1, %2, %3 op_sel:[0,1,0] op_sel_hi:[1,1,1] neg_lo:[0,1,0] neg_hi:[0,1,0]"
        : "=v"(d) : "v"(a), "v"(cs), "v"(acc));
    return d;
}
__device__ __forceinline__ v2f pkfma_sw(v2f a, v2f cs, v2f acc) {
    // d.lo = -s*a.hi + acc.lo ; d.hi = s*a.lo + acc.hi
    v2f d;
    asm("v_pk_fma_f32 %0, %1, %2, %3 op_sel:[1,1,0] op_sel_hi:[0,1,1] neg_lo:[0,1,0] neg_hi:[0,0,0]"
        : "=v"(d) : "v"(a), "v"(cs), "v"(acc));
    return d;
}
__device__ __forceinline__ v2f pkfma(v2f a, v2f bb, v2f acc) {     // a*b + acc
    v2f d;
    asm("v_pk_fma_f32 %0, %1, %2, %3"
        : "=v"(d) : "v"(a), "v"(bb), "v"(acc));
    return d;
}

// wire on p-index bit 0 (intra register pair): 2 pk-instr per v2f
__device__ __forceinline__ void ry_pk0(float (&p)[16], v2f cs) {
#pragma unroll
    for (int j = 0; j < 8; ++j) {
        v2f v = *(v2f*)&p[2 * j];
        *(v2f*)&p[2 * j] = pkfma_sw(v, cs, pkmul_cc(v, cs));
    }
}
// wire on p-index bit JB (1..3): 4 pk-instr per v2f pair
template <int JB>
__device__ __forceinline__ void ry_pkN(float (&p)[16], v2f cs) {
#pragma unroll
    for (int j = 0; j < 8; ++j) {
        if (!((j >> (JB - 1)) & 1)) {
            const int j1 = j | (1 << (JB - 1));
            v2f a0 = *(v2f*)&p[2 * j], a1 = *(v2f*)&p[2 * j1];
            *(v2f*)&p[2 * j]  = pkfma_nss(a1, cs, pkmul_cc(a0, cs));
            *(v2f*)&p[2 * j1] = pkfma_cc(a1, cs, pkmul_ss(a0, cs));
        }
    }
}
__device__ __forceinline__ void ry4_pk(float (&p)[16], float2 q0, float2 q1,
                                       float2 q2, float2 q3) {
    v2f c0, c1, c2, c3;
    c0.x = q0.x; c0.y = q0.y;
    c1.x = q1.x; c1.y = q1.y;
    c2.x = q2.x; c2.y = q2.y;
    c3.x = q3.x; c3.y = q3.y;
    ry_pk0(p, c0);
    ry_pkN<1>(p, c1);
    ry_pkN<2>(p, c2);
    ry_pkN<3>(p, c3);
}

// RY across lane bit 0/1 via DPP quad_perm, pk arithmetic (r11-proven form).
// CTRL: 0xB1 = xor lane^1, 0x4E = xor lane^2.  sg = (lane bit set)? +s : -s
template <int CTRL>
__device__ __forceinline__ void ry_dpp_pk(float (&p)[16], float c, float sg) {
    v2f cs; cs.x = c; cs.y = 0.0f;
    v2f sgv; sgv.x = sg; sgv.y = sg;
#pragma unroll
    for (int j = 0; j < 8; ++j) {
        v2f pt;
        pt.x = __int_as_float(__builtin_amdgcn_update_dpp(
            0, __float_as_int(p[2 * j]), CTRL, 0xF, 0xF, true));
        pt.y = __int_as_float(__builtin_amdgcn_update_dpp(
            0, __float_as_int(p[2 * j + 1]), CTRL, 0xF, 0xF, true));
        v2f v = *(v2f*)&p[2 * j];
        *(v2f*)&p[2 * j] = pkfma(pt, sgv, pkmul_cc(v, cs));
    }
}

// product state (H + data RYs) evaluated at sigma((block<<4)|i)
__device__ __forceinline__ void init_product(const float2* __restrict__ xfs,
                                             int mt, float (&p)[16]) {
    float sh = 1.0f / 128.0f;
#pragma unroll
    for (int j = 4; j < 14; ++j) {
        float2 f = xfs[j];
        sh *= ((mt >> j) & 1) ? f.y : f.x;
    }
    float fa[4], fb[4];
#pragma unroll
    for (int j = 0; j < 4; ++j) {
        float2 f = xfs[j];
        const int mj = (mt >> j) & 1;
        fa[j] = mj ? f.y : f.x;
        fb[j] = mj ? f.x : f.y;
    }
#pragma unroll
    for (int i = 0; i < 16; ++i) {
        const int sl = sigma(i);
        float v = sh;
        v *= (sl & 1)        ? fb[0] : fa[0];
        v *= ((sl >> 1) & 1) ? fb[1] : fa[1];
        v *= ((sl >> 2) & 1) ? fb[2] : fa[2];
        v *= ((sl >> 3) & 1) ? fb[3] : fa[3];
        p[i] = v;
    }
}

// expectations for one sample (real state: B drops out)
__device__ __forceinline__ void expect2(const float* __restrict__ stt,
                                        const float* __restrict__ A,
                                        const float* __restrict__ D,
                                        int t, float& E0, float& E1) {
    float e[2];
#pragma unroll
    for (int q = 0; q < 2; ++q) {
        const int shift = 11 - q;
        float dg[8];
#pragma unroll
        for (int i = 0; i < 7; ++i) dg[i] = 2.0f * D[q * 8 + i + 1];
        dg[7] = 0.0f;
        float acc = 0.0f;
        const int lowmask = (1 << shift) - 1;
        for (int r = t; r < NSTATE / 8; r += NT) {   // 2 iterations
            const int base = ((r >> shift) << (shift + 3)) | (r & lowmask);
            float ps[8];
#pragma unroll
            for (int i = 0; i < 8; ++i) ps[i] = stt[swz(base + (i << shift))];
#pragma unroll
            for (int i = 0; i < 8; ++i) acc += dg[i] * ps[i] * ps[i];
            int kk = 0;
#pragma unroll
            for (int i = 1; i < 8; ++i)
#pragma unroll
                for (int j = 0; j < i; ++j, ++kk)
                    acc += 2.0f * A[q * 28 + kk] * ps[i] * ps[j];
        }
        e[q] = acc;
    }
    E0 = e[0];
    E1 = e[1];
}

__global__ __launch_bounds__(NT, 4)
void vqc_kernel(const float* __restrict__ X,    // (512,14)
                const float* __restrict__ TH,   // (6,14)
                const float* __restrict__ A,    // (14,28)
                const float* __restrict__ Bc,   // (14,28)  unused: state stays real
                const float* __restrict__ D,    // (14,8)
                float* __restrict__ out)        // (512,2)
{
    __shared__ __align__(16) float st[2][NSTATE];   // 128 KiB: 2 samples/block
    __shared__ float2 tb[DEPTH * NQ];               // (cos,sin) per theta (shared)
    __shared__ float2 xf[2][NQ];                    // per-sample data factors
    __shared__ float  red[4 * (NT / 64)];

    const int t  = threadIdx.x;
    const int b0 = blockIdx.x * 2;

    // ---- trig tables ----
    if (t < DEPTH * NQ) {
        float s, c;
        __sincosf(0.5f * TH[t], &s, &c);
        tb[t] = make_float2(c, s);
    } else if (t < DEPTH * NQ + 2 * NQ) {
        const int j  = t - DEPTH * NQ;              // 0..27
        const int sm = j < NQ ? 0 : 1;
        const int jj = j < NQ ? j : j - NQ;         // amp bit <-> wire 13-jj
        float s, c;
        __sincosf(0.5f * X[(b0 + sm) * NQ + (13 - jj)], &s, &c);
        xf[sm][jj] = make_float2(c - s, c + s);
    }
    __syncthreads();

    float pA[16], pB[16];

    // ---- layer 0 P1: product state at sigma(n), rotate wires 13..10 ----
    {
        const int mt = sigma(t << 4);
        init_product(xf[0], mt, pA);
        init_product(xf[1], mt, pB);
        ry4_pk(pA, tb[13], tb[12], tb[11], tb[10]);
        ry4_pk(pB, tb[13], tb[12], tb[11], tb[10]);
        const int wb = swz(t << 4);
#pragma unroll
        for (int g = 0; g < 4; ++g) {
            *(float4*)&st[0][wb ^ (g << 2)] =
                make_float4(pA[4 * g], pA[4 * g + 1], pA[4 * g + 2], pA[4 * g + 3]);
            *(float4*)&st[1][wb ^ (g << 2)] =
                make_float4(pB[4 * g], pB[4 * g + 1], pB[4 * g + 2], pB[4 * g + 3]);
        }
    }
    __syncthreads();

    // ---- layers: P1 (CNOT + 13-10), P2 (9-6 reg + 5,4 DPP), P3 (3-0) ----
    for (int k = 0; k < DEPTH; ++k) {
        const float2* tbk = tb + k * NQ;

        if (k > 0) {
            // P1: gather through sigma (b128); lane XOR 12 folded into address.
            const int rb = swz(sigma(t << 4) & ~15) ^ ((t & 1) * 12);
            float tA[16], tB[16];
#pragma unroll
            for (int g = 0; g < 4; ++g) {
                *(float4*)&tA[g * 4] = *(const float4*)&st[0][rb ^ (g << 2)];
                *(float4*)&tB[g * 4] = *(const float4*)&st[1][rb ^ (g << 2)];
            }
#pragma unroll
            for (int i = 0; i < 16; ++i) {
                const int i0 = i & 1, i1 = (i >> 1) & 1, i2 = (i >> 2) & 1, i3 = (i >> 3) & 1;
                const int s = (i0 ^ i1 ^ i2) | ((i1 ^ i2) << 1) | ((i2 ^ i3) << 2) | (i3 << 3);
                pA[i] = tA[s];                   // compile-time shuffle
                pB[i] = tB[s];
            }
            __syncthreads();                     // all gather-reads before any write
            ry4_pk(pA, tbk[13], tbk[12], tbk[11], tbk[10]);
            ry4_pk(pB, tbk[13], tbk[12], tbk[11], tbk[10]);
            const int wb = swz(t << 4);
#pragma unroll
            for (int g = 0; g < 4; ++g) {
                *(float4*)&st[0][wb ^ (g << 2)] =
                    make_float4(pA[4 * g], pA[4 * g + 1], pA[4 * g + 2], pA[4 * g + 3]);
                *(float4*)&st[1][wb ^ (g << 2)] =
                    make_float4(pB[4 * g], pB[4 * g + 1], pB[4 * g + 2], pB[4 * g + 3]);
            }
            __syncthreads();
        }

        // P2: in-place RMW; regs = amp 4-7 (wires 9-6), DPP lanes 0,1 = amps 8,9
        {
            const int raw = ((t >> 2) & 15) | ((t & 1) << 8) | ((t & 2) << 8)
                          | (((t >> 6) & 15) << 10);
            const int base2 = swz(raw);
#pragma unroll
            for (int ip = 0; ip < 16; ++ip) {
                if ((ip & 2) == 0) {
                    const int v = base2 ^ (ip << 4) ^ (ip & 12);   // swz(ip<<4) folded
                    pA[ip]     = st[0][v];
                    pA[ip | 2] = st[0][v + 32];
                    pB[ip]     = st[1][v];
                    pB[ip | 2] = st[1][v + 32];
                }
            }
            ry4_pk(pA, tbk[9], tbk[8], tbk[7], tbk[6]);
            ry4_pk(pB, tbk[9], tbk[8], tbk[7], tbk[6]);
            float2 w5 = tbk[5], w4 = tbk[4];
            const float sg5 = (t & 1) ? w5.y : -w5.y;   // amp8 = lane bit 0
            const float sg4 = (t & 2) ? w4.y : -w4.y;   // amp9 = lane bit 1
            ry_dpp_pk<0xB1>(pA, w5.x, sg5);
            ry_dpp_pk<0xB1>(pB, w5.x, sg5);
            ry_dpp_pk<0x4E>(pA, w4.x, sg4);
            ry_dpp_pk<0x4E>(pB, w4.x, sg4);
#pragma unroll
            for (int ip = 0; ip < 16; ++ip) {
                if ((ip & 2) == 0) {
                    const int v = base2 ^ (ip << 4) ^ (ip & 12);
                    st[0][v]      = pA[ip];
                    st[0][v + 32] = pA[ip | 2];
                    st[1][v]      = pB[ip];
                    st[1][v + 32] = pB[ip | 2];
                }
            }
            __syncthreads();
        }

        // P3: in-place RMW; regs = amp 10-13 (wires 3-0), additive addresses.
        {
            const int base3 = swz(t);
#pragma unroll
            for (int i = 0; i < 16; ++i) {
                pA[i] = st[0][base3 + (i << 10)];
                pB[i] = st[1][base3 + (i << 10)];
            }
            ry4_pk(pA, tbk[3], tbk[2], tbk[1], tbk[0]);
            ry4_pk(pB, tbk[3], tbk[2], tbk[1], tbk[0]);
#pragma unroll
            for (int i = 0; i < 16; ++i) {
                st[0][base3 + (i << 10)] = pA[i];
                st[1][base3 + (i << 10)] = pB[i];
            }
            __syncthreads();
        }
    }

    // ---- expectations, both samples ----
    float eA0, eA1, eB0, eB1;
    expect2(st[0], A, D, t, eA0, eA1);
    expect2(st[1], A, D, t, eB0, eB1);

    // ---- block reduction (4 scalars) ----
#pragma unroll
    for (int o = 32; o > 0; o >>= 1) {
        eA0 += __shfl_down(eA0, o);
        eA1 += __shfl_down(eA1, o);
        eB0 += __shfl_down(eB0, o);
        eB1 += __shfl_down(eB1, o);
    }
    if ((t & 63) == 0) {
        red[(t >> 6) * 4 + 0] = eA0;
        red[(t >> 6) * 4 + 1] = eA1;
        red[(t >> 6) * 4 + 2] = eB0;
        red[(t >> 6) * 4 + 3] = eB1;
    }
    __syncthreads();
    if (t == 0) {
        float s0 = 0.0f, s1 = 0.0f, s2 = 0.0f, s3 = 0.0f;
#pragma unroll
        for (int i = 0; i < NT / 64; ++i) {
            s0 += red[i * 4 + 0];
            s1 += red[i * 4 + 1];
            s2 += red[i * 4 + 2];
            s3 += red[i * 4 + 3];
        }
        out[b0 * 2 + 0]       = s0;
        out[b0 * 2 + 1]       = s1;
        out[(b0 + 1) * 2 + 0] = s2;
        out[(b0 + 1) * 2 + 1] = s3;
    }
}

extern "C" void kernel_launch(void* const* d_in, const int* in_sizes, int n_in,
                              void* d_out, int out_size, void* d_ws, size_t ws_size,
                              hipStream_t stream) {
    const float* X  = (const float*)d_in[0];
    const float* TH = (const float*)d_in[1];
    const float* A  = (const float*)d_in[2];
    const float* Bc = (const float*)d_in[3];
    const float* D  = (const float*)d_in[4];
    float* out = (float*)d_out;
    vqc_kernel<<<256, NT, 0, stream>>>(X, TH, A, Bc, D, out);
}

// Round 17
// 49.107 us; speedup vs baseline: 1.0128x; 1.0128x over previous
//
#include <hip/hip_runtime.h>
#include <math.h>

#define NQ 14
#define NSTATE (1 << 14)
#define DEPTH  6
#define NT     1024             // 16 waves/block; 2 blocks/CU (64 KiB state each)

typedef float v2f __attribute__((ext_vector_type(2)));

// dword-index swizzle: XOR bits 6,7,8 into 2,3,4 (GF(2)-linear)
__device__ __forceinline__ int swz(int n) { return n ^ ((n >> 4) & 28); }

// fused CNOT ladders (even after odd): m = sigma_e(sigma_o(n))
__device__ __forceinline__ int sigma(int n) {
    int m = n ^ ((n & 0x1554) >> 1);
    return m ^ ((m & 0x2AAA) >> 1);
}

// ---- VOP3P packed helpers (r11/r15-proven); cs = (c, s) ----
__device__ __forceinline__ v2f pkmul_cc(v2f a, v2f cs) {   // d = a * c
    v2f d;
    asm("v_pk_mul_f32 %0, %1, %2 op_sel:[0,0] op_sel_hi:[1,0]"
        : "=v"(d) : "v"(a), "v"(cs));
    return d;
}
__device__ __forceinline__ v2f pkmul_ss(v2f a, v2f cs) {   // d = a * s
    v2f d;
    asm("v_pk_mul_f32 %0, %1, %2 op_sel:[0,1] op_sel_hi:[1,1]"
        : "=v"(d) : "v"(a), "v"(cs));
    return d;
}
__device__ __forceinline__ v2f pkfma_cc(v2f a, v2f cs, v2f acc) {  // a*c + acc
    v2f d;
    asm("v_pk_fma_f32 %0, %1, %2, %3 op_sel:[0,0,0] op_sel_hi:[1,0,1]"
        : "=v"(d) : "v"(a), "v"(cs), "v"(acc));
    return d;
}
__device__ __forceinline__ v2f pkfma_nss(v2f a, v2f cs, v2f acc) { // -(a*s) + acc
    v2f d;
    asm("v_pk_fma_f32 %0, %1, %2, %3 op_sel:[0,1,0] op_sel_hi:[1,1,1] neg_lo:[0,1,0] neg_hi:[0,1,0]"
        : "=v"(d) : "v"(a), "v"(cs), "v"(acc));
    return d;
}
__device__ __forceinline__ v2f pkfma_sw(v2f a, v2f cs, v2f acc) {
    // d.lo = -s*a.hi + acc.lo ; d.hi = s*a.lo + acc.hi
    v2f d;
    asm("v_pk_fma_f32 %0, %1, %2, %3 op_sel:[1,1,0] op_sel_hi:[0,1,1] neg_lo:[0,1,0] neg_hi:[0,0,0]"
        : "=v"(d) : "v"(a), "v"(cs), "v"(acc));
    return d;
}
__device__ __forceinline__ v2f pkfma(v2f a, v2f bb, v2f acc) {     // a*b + acc
    v2f d;
    asm("v_pk_fma_f32 %0, %1, %2, %3"
        : "=v"(d) : "v"(a), "v"(bb), "v"(acc));
    return d;
}

// wire on p-index bit 0 (intra register pair): 2 pk-instr per v2f
__device__ __forceinline__ void ry_pk0(float (&p)[16], v2f cs) {
#pragma unroll
    for (int j = 0; j < 8; ++j) {
        v2f v = *(v2f*)&p[2 * j];
        *(v2f*)&p[2 * j] = pkfma_sw(v, cs, pkmul_cc(v, cs));
    }
}
// wire on p-index bit JB (1..3): 4 pk-instr per v2f pair
template <int JB>
__device__ __forceinline__ void ry_pkN(float (&p)[16], v2f cs) {
#pragma unroll
    for (int j = 0; j < 8; ++j) {
        if (!((j >> (JB - 1)) & 1)) {
            const int j1 = j | (1 << (JB - 1));
            v2f a0 = *(v2f*)&p[2 * j], a1 = *(v2f*)&p[2 * j1];
            *(v2f*)&p[2 * j]  = pkfma_nss(a1, cs, pkmul_cc(a0, cs));
            *(v2f*)&p[2 * j1] = pkfma_cc(a1, cs, pkmul_ss(a0, cs));
        }
    }
}
__device__ __forceinline__ void ry4_pk(float (&p)[16], float2 q0, float2 q1,
                                       float2 q2, float2 q3) {
    v2f c0, c1, c2, c3;
    c0.x = q0.x; c0.y = q0.y;
    c1.x = q1.x; c1.y = q1.y;
    c2.x = q2.x; c2.y = q2.y;
    c3.x = q3.x; c3.y = q3.y;
    ry_pk0(p, c0);
    ry_pkN<1>(p, c1);
    ry_pkN<2>(p, c2);
    ry_pkN<3>(p, c3);
}

// wire on lane bit 0/1 (one DPP mov per scalar): CTRL 0xB1 = xor1, 0x4E = xor2
template <int CTRL>
__device__ __forceinline__ void ry_dpp_pk(float (&p)[16], float c, float sg) {
    v2f cs; cs.x = c; cs.y = 0.0f;
    v2f sgv; sgv.x = sg; sgv.y = sg;
#pragma unroll
    for (int j = 0; j < 8; ++j) {
        v2f pt;
        pt.x = __int_as_float(__builtin_amdgcn_update_dpp(
            0, __float_as_int(p[2 * j]), CTRL, 0xF, 0xF, true));
        pt.y = __int_as_float(__builtin_amdgcn_update_dpp(
            0, __float_as_int(p[2 * j + 1]), CTRL, 0xF, 0xF, true));
        v2f v = *(v2f*)&p[2 * j];
        *(v2f*)&p[2 * j] = pkfma(pt, sgv, pkmul_cc(v, cs));
    }
}

// wire on lane bit 2/3 via 2-mov DPP composite (XOR masks compose):
// xor4 = quad_perm 0x1B (xor3) . row_half_mirror 0x141 (xor7)
// xor8 = row_half_mirror 0x141 (xor7) . row_mirror 0x140 (xor15)
template <int C1, int C2>
__device__ __forceinline__ void ry_dpp2_pk(float (&p)[16], float c, float sg) {
    v2f cs; cs.x = c; cs.y = 0.0f;
    v2f sgv; sgv.x = sg; sgv.y = sg;
#pragma unroll
    for (int j = 0; j < 8; ++j) {
        v2f pt;
        int ax = __builtin_amdgcn_update_dpp(
            0, __float_as_int(p[2 * j]), C1, 0xF, 0xF, true);
        pt.x = __int_as_float(__builtin_amdgcn_update_dpp(
            0, ax, C2, 0xF, 0xF, true));
        int ay = __builtin_amdgcn_update_dpp(
            0, __float_as_int(p[2 * j + 1]), C1, 0xF, 0xF, true);
        pt.y = __int_as_float(__builtin_amdgcn_update_dpp(
            0, ay, C2, 0xF, 0xF, true));
        v2f v = *(v2f*)&p[2 * j];
        *(v2f*)&p[2 * j] = pkfma(pt, sgv, pkmul_cc(v, cs));
    }
}

__global__ __launch_bounds__(NT, 4)
void vqc_kernel(const float* __restrict__ X,    // (512,14)
                const float* __restrict__ TH,   // (6,14)
                const float* __restrict__ A,    // (14,28)
                const float* __restrict__ Bc,   // (14,28)  unused: state stays real
                const float* __restrict__ D,    // (14,8)
                float* __restrict__ out)        // (512,2)
{
    __shared__ __align__(16) float st[NSTATE];  // 64 KiB real state
    __shared__ float2 tb[DEPTH * NQ];           // (cos,sin) per theta
    __shared__ float2 xf[NQ];                   // (c-s, c+s) per amplitude bit j
    __shared__ float  red[2 * (NT / 64)];

    const int t = threadIdx.x;
    const int b = blockIdx.x;

    // ---- trig tables (uniform work once per block) ----
    if (t < DEPTH * NQ) {
        float s, c;
        __sincosf(0.5f * TH[t], &s, &c);
        tb[t] = make_float2(c, s);
    } else if (t < DEPTH * NQ + NQ) {
        const int j = t - DEPTH * NQ;           // amplitude-bit j <-> wire 13-j
        float s, c;
        __sincosf(0.5f * X[b * NQ + (13 - j)], &s, &c);
        xf[j] = make_float2(c - s, c + s);
    }
    __syncthreads();

    // ---- layer 0 P1: product state at sigma(n); rotate wires 13-10 (reg)
    //      + wires 9,8 (amps 4,5 = lane bits 0,1, DPP) ----
    {
        const int mt = sigma(t << 4);
        float sh = 1.0f / 128.0f;
#pragma unroll
        for (int j = 4; j < 14; ++j) {
            float2 f = xf[j];
            sh *= ((mt >> j) & 1) ? f.y : f.x;
        }
        float fa[4], fb[4];
#pragma unroll
        for (int j = 0; j < 4; ++j) {
            float2 f = xf[j];
            const int mj = (mt >> j) & 1;
            fa[j] = mj ? f.y : f.x;
            fb[j] = mj ? f.x : f.y;
        }
        float p[16];
#pragma unroll
        for (int i = 0; i < 16; ++i) {
            const int sl = sigma(i);
            float v = sh;
            v *= (sl & 1)        ? fb[0] : fa[0];
            v *= ((sl >> 1) & 1) ? fb[1] : fa[1];
            v *= ((sl >> 2) & 1) ? fb[2] : fa[2];
            v *= ((sl >> 3) & 1) ? fb[3] : fa[3];
            p[i] = v;
        }
        ry4_pk(p, tb[13], tb[12], tb[11], tb[10]);
        float2 w9 = tb[9], w8 = tb[8];
        const float sg9 = (t & 1) ? w9.y : -w9.y;
        const float sg8 = (t & 2) ? w8.y : -w8.y;
        ry_dpp_pk<0xB1>(p, w9.x, sg9);
        ry_dpp_pk<0x4E>(p, w8.x, sg8);
        const int wb = swz(t << 4);
#pragma unroll
        for (int g = 0; g < 4; ++g)
            *(float4*)&st[wb ^ (g << 2)] =
                make_float4(p[4 * g], p[4 * g + 1], p[4 * g + 2], p[4 * g + 3]);
    }
    __syncthreads();

    // ---- layers: P1 (CNOT + wires 13-10 reg, 9,8 DPP);
    //              P2 (wires 3-0 reg, 7,6 DPP, 5,4 composite-DPP) ----
    for (int k = 0; k < DEPTH; ++k) {
        const float2* tbk = tb + k * NQ;

        if (k > 0) {
            // P1: gather through sigma (b128); lane XOR 12 folded into address;
            // in-block permute = compile-time register renaming.
            const int rb = swz(sigma(t << 4) & ~15) ^ ((t & 1) * 12);
            float tmpf[16];
#pragma unroll
            for (int g = 0; g < 4; ++g)
                *(float4*)&tmpf[g * 4] = *(const float4*)&st[rb ^ (g << 2)];
            float p[16];
#pragma unroll
            for (int i = 0; i < 16; ++i) {
                const int i0 = i & 1, i1 = (i >> 1) & 1, i2 = (i >> 2) & 1, i3 = (i >> 3) & 1;
                const int s = (i0 ^ i1 ^ i2) | ((i1 ^ i2) << 1) | ((i2 ^ i3) << 2) | (i3 << 3);
                p[i] = tmpf[s];
            }
            __syncthreads();                     // all gather-reads before any write
            ry4_pk(p, tbk[13], tbk[12], tbk[11], tbk[10]);
            float2 w9 = tbk[9], w8 = tbk[8];
            const float sg9 = (t & 1) ? w9.y : -w9.y;   // amp4 = lane bit 0
            const float sg8 = (t & 2) ? w8.y : -w8.y;   // amp5 = lane bit 1
            ry_dpp_pk<0xB1>(p, w9.x, sg9);
            ry_dpp_pk<0x4E>(p, w8.x, sg8);
            const int wb = swz(t << 4);
#pragma unroll
            for (int g = 0; g < 4; ++g)
                *(float4*)&st[wb ^ (g << 2)] =
                    make_float4(p[4 * g], p[4 * g + 1], p[4 * g + 2], p[4 * g + 3]);
            __syncthreads();
        }

        // P2: in-place RMW. Thread->amp map: d0,d1<-t4,t5; d2-d5<-t6-t9;
        // d6,d7<-t0,t1; d8,d9<-t2,t3; regs = amps 10-13 (i<<10, additive).
        // Banks: lanes {4,5,0,1,2} hit 32 banks; lane3 -> d9 (non-bank) = 2-way free.
        {
            const int raw = ((t >> 4) & 3) | (((t >> 6) & 15) << 2)
                          | ((t & 3) << 6) | (((t >> 2) & 3) << 8);
            const int base2 = swz(raw);
            float p[16];
#pragma unroll
            for (int i = 0; i < 16; ++i) p[i] = st[base2 + (i << 10)];
            // regs: p bits 0-3 = amps 10-13 = wires 3,2,1,0
            ry4_pk(p, tbk[3], tbk[2], tbk[1], tbk[0]);
            float2 w7 = tbk[7], w6 = tbk[6], w5 = tbk[5], w4 = tbk[4];
            const float sg7 = (t & 1) ? w7.y : -w7.y;   // amp6 = lane bit 0
            const float sg6 = (t & 2) ? w6.y : -w6.y;   // amp7 = lane bit 1
            const float sg5 = (t & 4) ? w5.y : -w5.y;   // amp8 = lane bit 2
            const float sg4 = (t & 8) ? w4.y : -w4.y;   // amp9 = lane bit 3
            ry_dpp_pk<0xB1>(p, w7.x, sg7);
            ry_dpp_pk<0x4E>(p, w6.x, sg6);
            ry_dpp2_pk<0x1B, 0x141>(p, w5.x, sg5);      // xor3 ^ xor7 = xor4
            ry_dpp2_pk<0x141, 0x140>(p, w4.x, sg4);     // xor7 ^ xor15 = xor8
#pragma unroll
            for (int i = 0; i < 16; ++i) st[base2 + (i << 10)] = p[i];
            __syncthreads();
        }
    }

    // ---- expectations (real state: B drops out) ----
    float e[2];
#pragma unroll
    for (int q = 0; q < 2; ++q) {
        const int shift = 11 - q;
        float dg[8];
#pragma unroll
        for (int i = 0; i < 7; ++i) dg[i] = 2.0f * D[q * 8 + i + 1];
        dg[7] = 0.0f;
        float acc = 0.0f;
        const int lowmask = (1 << shift) - 1;
        for (int r = t; r < NSTATE / 8; r += NT) {   // 2 iterations
            const int base = ((r >> shift) << (shift + 3)) | (r & lowmask);
            float ps[8];
#pragma unroll
            for (int i = 0; i < 8; ++i) ps[i] = st[swz(base + (i << shift))];
#pragma unroll
            for (int i = 0; i < 8; ++i) acc += dg[i] * ps[i] * ps[i];
            int kk = 0;
#pragma unroll
            for (int i = 1; i < 8; ++i)
#pragma unroll
                for (int j = 0; j < i; ++j, ++kk)
                    acc += 2.0f * A[q * 28 + kk] * ps[i] * ps[j];
        }
        e[q] = acc;
    }

    // ---- block reduction ----
    float v0 = e[0], v1 = e[1];
#pragma unroll
    for (int o = 32; o > 0; o >>= 1) {
        v0 += __shfl_down(v0, o);
        v1 += __shfl_down(v1, o);
    }
    if ((t & 63) == 0) {
        red[(t >> 6) * 2]     = v0;
        red[(t >> 6) * 2 + 1] = v1;
    }
    __syncthreads();
    if (t == 0) {
        float s0 = 0.0f, s1 = 0.0f;
#pragma unroll
        for (int i = 0; i < NT / 64; ++i) { s0 += red[i * 2]; s1 += red[i * 2 + 1]; }
        out[b * 2 + 0] = s0;
        out[b * 2 + 1] = s1;
    }
}

extern "C" void kernel_launch(void* const* d_in, const int* in_sizes, int n_in,
                              void* d_out, int out_size, void* d_ws, size_t ws_size,
                              hipStream_t stream) {
    const float* X  = (const float*)d_in[0];
    const float* TH = (const float*)d_in[1];
    const float* A  = (const float*)d_in[2];
    const float* Bc = (const float*)d_in[3];
    const float* D  = (const float*)d_in[4];
    float* out = (float*)d_out;
    vqc_kernel<<<512, NT, 0, stream>>>(X, TH, A, Bc, D, out);
}